// Round 3
// baseline (168.059 us; speedup 1.0000x reference)
//
#include <hip/hip_runtime.h>

// EdgeSumAggregatorSparse: out[b, t[e], d] += msgs[b, e, d]
// B=2, D=128 hard-coded; E, N derived at launch.

#define D_DIM 128
#define B_DIM 2
#define MAX_CAP 256

// ---------------------------------------------------------------- zero pass
__global__ void zero_kernel(float* __restrict__ out, size_t out_elems,
                            int* __restrict__ counts, int n_counts) {
    size_t i = (size_t)blockIdx.x * blockDim.x + threadIdx.x;
    size_t stride = (size_t)gridDim.x * blockDim.x;
    for (size_t j = i; j < out_elems; j += stride) out[j] = 0.0f;
    for (size_t j = i; j < (size_t)n_counts; j += stride) counts[j] = 0;
}

// ------------------------------------------------------------- bucket fill
// One thread per edge. Claims a slot in its target node's bucket via an int
// atomic. Overflow (> cap edges on one node) falls back to direct fp32
// atomics into out — correct for any input, ~never taken at cap=256, lambda=50.
__global__ void bucket_fill_kernel(const int* __restrict__ targets,
                                   const float* __restrict__ msgs,
                                   float* __restrict__ out,
                                   int* __restrict__ counts,
                                   int* __restrict__ buckets,
                                   int E, int N, int cap) {
    int e = blockIdx.x * blockDim.x + threadIdx.x;
    if (e >= E) return;
    int t = targets[e];
    int pos = atomicAdd(&counts[t], 1);
    if (pos < cap) {
        buckets[(size_t)t * cap + pos] = e;
    } else {
        // rare overflow path: direct scatter-add (out pre-zeroed)
        for (int b = 0; b < B_DIM; ++b) {
            const float* src = msgs + ((size_t)b * E + e) * D_DIM;
            float* dst = out + ((size_t)b * N + t) * D_DIM;
            for (int d = 0; d < D_DIM; ++d) atomicAdd(&dst[d], src[d]);
        }
    }
}

// ------------------------------------------------------------------ gather
// One WAVE per (node, batch) pair; 4 waves per 256-thread block so the CU
// workgroup-slot cap doesn't throttle occupancy (64-thread blocks cap at
// ~16 waves/CU; 256-thread blocks reach the full 32).
// Each lane holds a float2 slice: 64 lanes x 8B = one full 512B row per
// load instruction. Bucket ids are staged 64-at-a-time coalesced, then
// broadcast via __shfl with uniform j (readlane -> SGPR addressing).
__global__ __launch_bounds__(256) void gather_kernel(
        const float* __restrict__ msgs,
        const int* __restrict__ counts,
        const int* __restrict__ buckets,
        float* __restrict__ out,
        int E, int N, int cap) {
    int wave = threadIdx.x >> 6;           // 0..3
    int lane = threadIdx.x & 63;
    int pair = blockIdx.x * 4 + wave;      // (node, batch) work item
    if (pair >= 2 * N) return;
    int n = pair >> 1;
    int b = pair & 1;

    int cnt_raw = counts[n];
    int cnt = cnt_raw < cap ? cnt_raw : cap;
    const int* bk = buckets + (size_t)n * cap;

    float2 acc = make_float2(0.f, 0.f);
    const float* base = msgs + (size_t)b * E * D_DIM;

    for (int chunk = 0; chunk < cnt; chunk += 64) {
        int m = cnt - chunk;
        if (m > 64) m = 64;
        int my_e = (lane < m) ? bk[chunk + lane] : 0;   // coalesced stage
        #pragma unroll 8
        for (int j = 0; j < m; ++j) {
            int e = __shfl(my_e, j);                    // uniform -> readlane
            const float2* row = reinterpret_cast<const float2*>(base + (size_t)e * D_DIM);
            float2 v = row[lane];
            acc.x += v.x; acc.y += v.y;
        }
    }

    float2* o = reinterpret_cast<float2*>(out + ((size_t)b * N + n) * D_DIM) + lane;
    if (cnt_raw > cap) {
        // overflow contributions already atomically added into out: RMW
        float2 cur = *o;
        cur.x += acc.x; cur.y += acc.y;
        *o = cur;
    } else {
        *o = acc;   // sole writer for this (node,batch) row
    }
}

// --------------------------------------------------- fallback: pure atomics
__global__ void scatter_atomic_kernel(const float* __restrict__ msgs,
                                      const int* __restrict__ targets,
                                      float* __restrict__ out,
                                      int E, int N) {
    size_t total = (size_t)E * D_DIM;
    size_t stride = (size_t)gridDim.x * blockDim.x;
    for (size_t idx = (size_t)blockIdx.x * blockDim.x + threadIdx.x;
         idx < total; idx += stride) {
        int e = (int)(idx >> 7);
        int d = (int)(idx & (D_DIM - 1));
        int t = targets[e];
        atomicAdd(&out[((size_t)0 * N + t) * D_DIM + d],
                  msgs[((size_t)0 * E + e) * D_DIM + d]);
        atomicAdd(&out[((size_t)1 * N + t) * D_DIM + d],
                  msgs[((size_t)1 * E + e) * D_DIM + d]);
    }
}

extern "C" void kernel_launch(void* const* d_in, const int* in_sizes, int n_in,
                              void* d_out, int out_size, void* d_ws, size_t ws_size,
                              hipStream_t stream) {
    const float* msgs    = (const float*)d_in[0];
    const int*   targets = (const int*)d_in[1];
    float*       out     = (float*)d_out;

    const int E = in_sizes[1];
    const int N = out_size / (B_DIM * D_DIM);

    // workspace layout: [ counts: N ints ][ buckets: N*cap ints ]
    size_t ws_ints = ws_size / sizeof(int);
    long cap_l = ((long)ws_ints - N) / (N > 0 ? N : 1);
    int cap = (int)(cap_l < 0 ? 0 : (cap_l > MAX_CAP ? MAX_CAP : cap_l));

    size_t out_elems = (size_t)out_size;

    if (cap >= 8) {
        int* counts  = (int*)d_ws;
        int* buckets = counts + N;

        zero_kernel<<<2048, 256, 0, stream>>>(out, out_elems, counts, N);
        bucket_fill_kernel<<<(E + 255) / 256, 256, 0, stream>>>(
            targets, msgs, out, counts, buckets, E, N, cap);
        int pairs = 2 * N;
        gather_kernel<<<(pairs + 3) / 4, 256, 0, stream>>>(
            msgs, counts, buckets, out, E, N, cap);
    } else {
        // tiny-workspace fallback: correctness over speed
        int* counts = (int*)d_ws;  // unused
        zero_kernel<<<2048, 256, 0, stream>>>(out, out_elems, counts, 0);
        scatter_atomic_kernel<<<4096, 256, 0, stream>>>(msgs, targets, out, E, N);
    }
}

// Round 4
// 144.699 us; speedup vs baseline: 1.1614x; 1.1614x over previous
//
#include <hip/hip_runtime.h>

// EdgeSumAggregatorSparse: out[b, t[e], d] += msgs[b, e, d]
// B=2, D=128 hard-coded; E, N derived at launch.

typedef float f32x4 __attribute__((ext_vector_type(4)));

#define D_DIM 128
#define B_DIM 2
#define MAX_CAP 256

// ---------------------------------------------------------------- zero pass
__global__ void zero_kernel(float* __restrict__ out, size_t out_elems,
                            int* __restrict__ counts, int n_counts) {
    size_t i = (size_t)blockIdx.x * blockDim.x + threadIdx.x;
    size_t stride = (size_t)gridDim.x * blockDim.x;
    size_t nv = out_elems / 4;
    f32x4* o4 = reinterpret_cast<f32x4*>(out);
    f32x4 z = 0.f;
    for (size_t j = i; j < nv; j += stride) __builtin_nontemporal_store(z, &o4[j]);
    for (size_t j = nv * 4 + i; j < out_elems; j += stride) out[j] = 0.f;
    for (size_t j = i; j < (size_t)n_counts; j += stride) counts[j] = 0;
}

// ------------------------------------------------------------- bucket fill
// One thread per edge; int atomic claims a slot in the target node's bucket.
// NT store for the scattered 4B bucket write (no write-allocate line fetch).
// Overflow (> cap edges on a node) falls back to direct fp32 atomics into
// out — correct for any input, ~never taken at cap=256, lambda=50.
__global__ void bucket_fill_kernel(const int* __restrict__ targets,
                                   const float* __restrict__ msgs,
                                   float* __restrict__ out,
                                   int* __restrict__ counts,
                                   int* __restrict__ buckets,
                                   int E, int N, int cap) {
    int e = blockIdx.x * blockDim.x + threadIdx.x;
    if (e >= E) return;
    int t = __builtin_nontemporal_load(&targets[e]);
    int pos = atomicAdd(&counts[t], 1);
    if (pos < cap) {
        __builtin_nontemporal_store(e, &buckets[(size_t)t * cap + pos]);
    } else {
        for (int b = 0; b < B_DIM; ++b) {
            const float* src = msgs + ((size_t)b * E + e) * D_DIM;
            float* dst = out + ((size_t)b * N + t) * D_DIM;
            for (int d = 0; d < D_DIM; ++d) atomicAdd(&dst[d], src[d]);
        }
    }
}

// ------------------------------------------------------------------ gather
// One wave per node, 4 waves per 256-thread block.
// lane -> (batch = lane>>5, float4 slot q = lane&31): one wave instruction
// reads BOTH batch rows of an edge = 2 x 512B = 1KB (16B/lane, max width).
// Bucket ids staged 64-at-a-time coalesced, broadcast via __shfl(uniform j)
// -> readlane/SGPR addressing; unroll 8 for deep MLP. NT loads: every msgs
// row is single-use, keep L2/L3 for buckets+counts.
__global__ __launch_bounds__(256) void gather_kernel(
        const float* __restrict__ msgs,
        const int* __restrict__ counts,
        const int* __restrict__ buckets,
        float* __restrict__ out,
        int E, int N, int cap) {
    int wave = threadIdx.x >> 6;
    int lane = threadIdx.x & 63;
    int n = blockIdx.x * 4 + wave;
    if (n >= N) return;
    int b = lane >> 5;    // batch
    int q = lane & 31;    // float4 slot within the 128-float row

    int cnt_raw = counts[n];
    int cnt = cnt_raw < cap ? cnt_raw : cap;
    const int* bk = buckets + (size_t)n * cap;

    f32x4 acc = 0.f;
    const float* base = msgs + (size_t)b * E * D_DIM;

    for (int chunk = 0; chunk < cnt; chunk += 64) {
        int m = cnt - chunk;
        if (m > 64) m = 64;
        int my_e = (lane < m) ? bk[chunk + lane] : 0;   // coalesced stage
        #pragma unroll 8
        for (int j = 0; j < m; ++j) {
            int e = __shfl(my_e, j);                    // uniform -> readlane
            const f32x4* row = reinterpret_cast<const f32x4*>(base + (size_t)e * D_DIM);
            acc += __builtin_nontemporal_load(&row[q]);
        }
    }

    f32x4* o = reinterpret_cast<f32x4*>(out + ((size_t)b * N + n) * D_DIM) + q;
    if (cnt_raw > cap) {
        // overflow contributions already atomically added into out: RMW
        f32x4 cur = *o;
        *o = cur + acc;
    } else {
        __builtin_nontemporal_store(acc, o);   // sole writer, never re-read
    }
}

// --------------------------------------------------- fallback: pure atomics
__global__ void scatter_atomic_kernel(const float* __restrict__ msgs,
                                      const int* __restrict__ targets,
                                      float* __restrict__ out,
                                      int E, int N) {
    size_t total = (size_t)E * D_DIM;
    size_t stride = (size_t)gridDim.x * blockDim.x;
    for (size_t idx = (size_t)blockIdx.x * blockDim.x + threadIdx.x;
         idx < total; idx += stride) {
        int e = (int)(idx >> 7);
        int d = (int)(idx & (D_DIM - 1));
        int t = targets[e];
        atomicAdd(&out[((size_t)0 * N + t) * D_DIM + d],
                  msgs[((size_t)0 * E + e) * D_DIM + d]);
        atomicAdd(&out[((size_t)1 * N + t) * D_DIM + d],
                  msgs[((size_t)1 * E + e) * D_DIM + d]);
    }
}

extern "C" void kernel_launch(void* const* d_in, const int* in_sizes, int n_in,
                              void* d_out, int out_size, void* d_ws, size_t ws_size,
                              hipStream_t stream) {
    const float* msgs    = (const float*)d_in[0];
    const int*   targets = (const int*)d_in[1];
    float*       out     = (float*)d_out;

    const int E = in_sizes[1];
    const int N = out_size / (B_DIM * D_DIM);

    // workspace layout: [ counts: N ints ][ buckets: N*cap ints ]
    size_t ws_ints = ws_size / sizeof(int);
    long cap_l = ((long)ws_ints - N) / (N > 0 ? N : 1);
    int cap = (int)(cap_l < 0 ? 0 : (cap_l > MAX_CAP ? MAX_CAP : cap_l));

    size_t out_elems = (size_t)out_size;

    if (cap >= 8) {
        int* counts  = (int*)d_ws;
        int* buckets = counts + N;

        zero_kernel<<<2048, 256, 0, stream>>>(out, out_elems, counts, N);
        bucket_fill_kernel<<<(E + 255) / 256, 256, 0, stream>>>(
            targets, msgs, out, counts, buckets, E, N, cap);
        gather_kernel<<<(N + 3) / 4, 256, 0, stream>>>(
            msgs, counts, buckets, out, E, N, cap);
    } else {
        // tiny-workspace fallback: correctness over speed
        int* counts = (int*)d_ws;  // unused
        zero_kernel<<<2048, 256, 0, stream>>>(out, out_elems, counts, 0);
        scatter_atomic_kernel<<<4096, 256, 0, stream>>>(msgs, targets, out, E, N);
    }
}

// Round 5
// 138.583 us; speedup vs baseline: 1.2127x; 1.0441x over previous
//
#include <hip/hip_runtime.h>

// EdgeSumAggregatorSparse: out[b, t[e], d] += msgs[b, e, d]
// B=2, D=128 hard-coded; E, N derived at launch.

typedef float f32x4 __attribute__((ext_vector_type(4)));

#define D_DIM 128
#define B_DIM 2
#define NSUB 4          // sub-counters per node (atomic contention spread)
#define MAX_SEG 64      // bucket slots per sub-counter (total cap = 256)

// ---------------------------------------------------------------- zero pass
__global__ void zero_kernel(float* __restrict__ out, size_t out_elems,
                            int* __restrict__ counts, int n_counts) {
    size_t i = (size_t)blockIdx.x * blockDim.x + threadIdx.x;
    size_t stride = (size_t)gridDim.x * blockDim.x;
    size_t nv = out_elems / 4;
    f32x4* o4 = reinterpret_cast<f32x4*>(out);
    f32x4 z = 0.f;
    for (size_t j = i; j < nv; j += stride) __builtin_nontemporal_store(z, &o4[j]);
    for (size_t j = nv * 4 + i; j < out_elems; j += stride) out[j] = 0.f;
    for (size_t j = i; j < (size_t)n_counts; j += stride) counts[j] = 0;
}

// ------------------------------------------------------------- bucket fill
// One thread per edge. counts layout: [NSUB][N]; thread picks sub-counter
// s = e & (NSUB-1), claims a slot in segment s of node t's bucket
// (bucket row = NSUB*seg ints). Cached (non-NT) bucket stores: a 64B line
// holds 16 slots of one segment and is written ~12x before eviction, and
// stays L2/L3-resident for the gather. Overflow of a segment falls back to
// direct fp32 atomics into out (pre-zeroed) — correct for any input.
__global__ void bucket_fill_kernel(const int* __restrict__ targets,
                                   const float* __restrict__ msgs,
                                   float* __restrict__ out,
                                   int* __restrict__ counts,
                                   int* __restrict__ buckets,
                                   int E, int N, int seg) {
    int e = blockIdx.x * blockDim.x + threadIdx.x;
    if (e >= E) return;
    int t = __builtin_nontemporal_load(&targets[e]);
    int s = e & (NSUB - 1);
    int pos = atomicAdd(&counts[s * N + t], 1);
    if (pos < seg) {
        buckets[(size_t)t * (NSUB * seg) + s * seg + pos] = e;
    } else {
        for (int b = 0; b < B_DIM; ++b) {
            const float* src = msgs + ((size_t)b * E + e) * D_DIM;
            float* dst = out + ((size_t)b * N + t) * D_DIM;
            for (int d = 0; d < D_DIM; ++d) atomicAdd(&dst[d], src[d]);
        }
    }
}

// ------------------------------------------------------------------ gather
// One wave per node, 4 waves per 256-thread block.
// lane -> (batch = lane>>5, float4 slot q = lane&31): one wave instruction
// reads BOTH batch rows of an edge = 2 x 512B = 1KB (16B/lane, max width).
// Walks the NSUB segments of the node's bucket back-to-back; ids staged
// 64-at-a-time coalesced, broadcast via __shfl(uniform j) -> readlane/SGPR
// addressing; unroll 8 for MLP. NT loads on msgs (single-use stream);
// buckets/counts read cached (L2/L3-resident from fill).
__global__ __launch_bounds__(256) void gather_kernel(
        const float* __restrict__ msgs,
        const int* __restrict__ counts,
        const int* __restrict__ buckets,
        float* __restrict__ out,
        int E, int N, int seg) {
    int wave = threadIdx.x >> 6;
    int lane = threadIdx.x & 63;
    int n = blockIdx.x * 4 + wave;
    if (n >= N) return;
    int b = lane >> 5;    // batch
    int q = lane & 31;    // float4 slot within the 128-float row

    f32x4 acc = 0.f;
    const float* base = msgs + (size_t)b * E * D_DIM;
    const int* bkrow = buckets + (size_t)n * (NSUB * seg);
    bool overflow = false;

    for (int s = 0; s < NSUB; ++s) {
        int cnt_raw = counts[s * N + n];
        int cnt = cnt_raw < seg ? cnt_raw : seg;
        overflow |= (cnt_raw > seg);
        const int* bk = bkrow + s * seg;
        for (int chunk = 0; chunk < cnt; chunk += 64) {
            int m = cnt - chunk;
            if (m > 64) m = 64;
            int my_e = (lane < m) ? bk[chunk + lane] : 0;   // coalesced stage
            #pragma unroll 8
            for (int j = 0; j < m; ++j) {
                int e = __shfl(my_e, j);                    // uniform -> readlane
                const f32x4* row = reinterpret_cast<const f32x4*>(base + (size_t)e * D_DIM);
                acc += __builtin_nontemporal_load(&row[q]);
            }
        }
    }

    f32x4* o = reinterpret_cast<f32x4*>(out + ((size_t)b * N + n) * D_DIM) + q;
    if (overflow) {
        // overflow contributions already atomically added into out: RMW
        f32x4 cur = *o;
        *o = cur + acc;
    } else {
        __builtin_nontemporal_store(acc, o);   // sole writer, never re-read
    }
}

// --------------------------------------------------- fallback: pure atomics
__global__ void scatter_atomic_kernel(const float* __restrict__ msgs,
                                      const int* __restrict__ targets,
                                      float* __restrict__ out,
                                      int E, int N) {
    size_t total = (size_t)E * D_DIM;
    size_t stride = (size_t)gridDim.x * blockDim.x;
    for (size_t idx = (size_t)blockIdx.x * blockDim.x + threadIdx.x;
         idx < total; idx += stride) {
        int e = (int)(idx >> 7);
        int d = (int)(idx & (D_DIM - 1));
        int t = targets[e];
        atomicAdd(&out[((size_t)0 * N + t) * D_DIM + d],
                  msgs[((size_t)0 * E + e) * D_DIM + d]);
        atomicAdd(&out[((size_t)1 * N + t) * D_DIM + d],
                  msgs[((size_t)1 * E + e) * D_DIM + d]);
    }
}

extern "C" void kernel_launch(void* const* d_in, const int* in_sizes, int n_in,
                              void* d_out, int out_size, void* d_ws, size_t ws_size,
                              hipStream_t stream) {
    const float* msgs    = (const float*)d_in[0];
    const int*   targets = (const int*)d_in[1];
    float*       out     = (float*)d_out;

    const int E = in_sizes[1];
    const int N = out_size / (B_DIM * D_DIM);

    // workspace layout: [ counts: NSUB*N ints ][ buckets: N*NSUB*seg ints ]
    size_t ws_ints = ws_size / sizeof(int);
    long seg_l = ((long)ws_ints - (long)NSUB * N) / ((long)NSUB * (N > 0 ? N : 1));
    int seg = (int)(seg_l < 0 ? 0 : (seg_l > MAX_SEG ? MAX_SEG : seg_l));

    size_t out_elems = (size_t)out_size;

    if (seg >= 4) {
        int* counts  = (int*)d_ws;
        int* buckets = counts + (size_t)NSUB * N;

        zero_kernel<<<2048, 256, 0, stream>>>(out, out_elems, counts, NSUB * N);
        bucket_fill_kernel<<<(E + 255) / 256, 256, 0, stream>>>(
            targets, msgs, out, counts, buckets, E, N, seg);
        gather_kernel<<<(N + 3) / 4, 256, 0, stream>>>(
            msgs, counts, buckets, out, E, N, seg);
    } else {
        // tiny-workspace fallback: correctness over speed
        int* counts = (int*)d_ws;  // unused
        zero_kernel<<<2048, 256, 0, stream>>>(out, out_elems, counts, 0);
        scatter_atomic_kernel<<<4096, 256, 0, stream>>>(msgs, targets, out, E, N);
    }
}

// Round 6
// 127.376 us; speedup vs baseline: 1.3194x; 1.0880x over previous
//
#include <hip/hip_runtime.h>

// EdgeSumAggregatorSparse: out[b, t[e], d] += msgs[b, e, d]
// B=2, D=128 hard-coded; E, N derived at launch.

typedef float f32x4 __attribute__((ext_vector_type(4)));

#define D_DIM 128
#define B_DIM 2
#define NSUB 4          // sub-counters per node (atomic contention spread)
#define MAX_SEG 64      // bucket slots per sub-counter (total cap = 256)

// ---------------------------------------------------------------- zero pass
__global__ void zero_kernel(float* __restrict__ out, size_t out_elems,
                            int* __restrict__ counts, int n_counts) {
    size_t i = (size_t)blockIdx.x * blockDim.x + threadIdx.x;
    size_t stride = (size_t)gridDim.x * blockDim.x;
    size_t nv = out_elems / 4;
    f32x4* o4 = reinterpret_cast<f32x4*>(out);
    f32x4 z = 0.f;
    for (size_t j = i; j < nv; j += stride) __builtin_nontemporal_store(z, &o4[j]);
    for (size_t j = nv * 4 + i; j < out_elems; j += stride) out[j] = 0.f;
    for (size_t j = i; j < (size_t)n_counts; j += stride) counts[j] = 0;
}

// ------------------------------------------------------------- bucket fill
// One thread per edge. counts layout: [NSUB][N]; thread picks sub-counter
// s = e & (NSUB-1), claims a slot in segment s of node t's bucket
// (bucket row = NSUB*seg ints). Cached (non-NT) bucket stores: 64B line
// holds 16 slots of one segment, written ~12x before eviction, stays
// L2/L3-resident for the gather. Segment overflow falls back to direct
// fp32 atomics into out (pre-zeroed) — correct for any input.
__global__ void bucket_fill_kernel(const int* __restrict__ targets,
                                   const float* __restrict__ msgs,
                                   float* __restrict__ out,
                                   int* __restrict__ counts,
                                   int* __restrict__ buckets,
                                   int E, int N, int seg) {
    int e = blockIdx.x * blockDim.x + threadIdx.x;
    if (e >= E) return;
    int t = __builtin_nontemporal_load(&targets[e]);
    int s = e & (NSUB - 1);
    int pos = atomicAdd(&counts[s * N + t], 1);
    if (pos < seg) {
        buckets[(size_t)t * (NSUB * seg) + s * seg + pos] = e;
    } else {
        for (int b = 0; b < B_DIM; ++b) {
            const float* src = msgs + ((size_t)b * E + e) * D_DIM;
            float* dst = out + ((size_t)b * N + t) * D_DIM;
            for (int d = 0; d < D_DIM; ++d) atomicAdd(&dst[d], src[d]);
        }
    }
}

// ------------------------------------------------------------------ gather
// One wave per node, 4 waves per 256-thread block.
// lane -> (batch = lane>>5, float4 slot q = lane&31): one wave instruction
// reads BOTH batch rows of an edge = 2 x 512B = 1KB (16B/lane).
// R5 experiment: TWO edges per iteration on TWO independent accumulator
// chains (acc0/acc1) so load consumption interleaves on separate vmcnt
// chains; unroll 4 pairs -> 8 x 1KB loads in flight per wave with half the
// serial dependency depth of R4. Discriminates issue-overhead-bound vs
// DRAM-efficiency-bound.
__global__ __launch_bounds__(256) void gather_kernel(
        const float* __restrict__ msgs,
        const int* __restrict__ counts,
        const int* __restrict__ buckets,
        float* __restrict__ out,
        int E, int N, int seg) {
    int wave = threadIdx.x >> 6;
    int lane = threadIdx.x & 63;
    int n = blockIdx.x * 4 + wave;
    if (n >= N) return;
    int b = lane >> 5;    // batch
    int q = lane & 31;    // float4 slot within the 128-float row

    f32x4 acc0 = 0.f, acc1 = 0.f;
    const float* base = msgs + (size_t)b * E * D_DIM;
    const int* bkrow = buckets + (size_t)n * (NSUB * seg);
    bool overflow = false;

    for (int s = 0; s < NSUB; ++s) {
        int cnt_raw = counts[s * N + n];
        int cnt = cnt_raw < seg ? cnt_raw : seg;
        overflow |= (cnt_raw > seg);
        const int* bk = bkrow + s * seg;
        for (int chunk = 0; chunk < cnt; chunk += 64) {
            int m = cnt - chunk;
            if (m > 64) m = 64;
            int my_e = (lane < m) ? bk[chunk + lane] : 0;   // coalesced stage
            int j = 0;
            #pragma unroll 4
            for (; j + 1 < m; j += 2) {
                int e0 = __shfl(my_e, j);                   // uniform -> readlane
                int e1 = __shfl(my_e, j + 1);
                const f32x4* r0 = reinterpret_cast<const f32x4*>(base + (size_t)e0 * D_DIM);
                const f32x4* r1 = reinterpret_cast<const f32x4*>(base + (size_t)e1 * D_DIM);
                acc0 += __builtin_nontemporal_load(&r0[q]);
                acc1 += __builtin_nontemporal_load(&r1[q]);
            }
            if (j < m) {
                int e0 = __shfl(my_e, j);
                const f32x4* r0 = reinterpret_cast<const f32x4*>(base + (size_t)e0 * D_DIM);
                acc0 += __builtin_nontemporal_load(&r0[q]);
            }
        }
    }

    f32x4 acc = acc0 + acc1;
    f32x4* o = reinterpret_cast<f32x4*>(out + ((size_t)b * N + n) * D_DIM) + q;
    if (overflow) {
        // overflow contributions already atomically added into out: RMW
        f32x4 cur = *o;
        *o = cur + acc;
    } else {
        __builtin_nontemporal_store(acc, o);   // sole writer, never re-read
    }
}

// --------------------------------------------------- fallback: pure atomics
__global__ void scatter_atomic_kernel(const float* __restrict__ msgs,
                                      const int* __restrict__ targets,
                                      float* __restrict__ out,
                                      int E, int N) {
    size_t total = (size_t)E * D_DIM;
    size_t stride = (size_t)gridDim.x * blockDim.x;
    for (size_t idx = (size_t)blockIdx.x * blockDim.x + threadIdx.x;
         idx < total; idx += stride) {
        int e = (int)(idx >> 7);
        int d = (int)(idx & (D_DIM - 1));
        int t = targets[e];
        atomicAdd(&out[((size_t)0 * N + t) * D_DIM + d],
                  msgs[((size_t)0 * E + e) * D_DIM + d]);
        atomicAdd(&out[((size_t)1 * N + t) * D_DIM + d],
                  msgs[((size_t)1 * E + e) * D_DIM + d]);
    }
}

extern "C" void kernel_launch(void* const* d_in, const int* in_sizes, int n_in,
                              void* d_out, int out_size, void* d_ws, size_t ws_size,
                              hipStream_t stream) {
    const float* msgs    = (const float*)d_in[0];
    const int*   targets = (const int*)d_in[1];
    float*       out     = (float*)d_out;

    const int E = in_sizes[1];
    const int N = out_size / (B_DIM * D_DIM);

    // workspace layout: [ counts: NSUB*N ints ][ buckets: N*NSUB*seg ints ]
    size_t ws_ints = ws_size / sizeof(int);
    long seg_l = ((long)ws_ints - (long)NSUB * N) / ((long)NSUB * (N > 0 ? N : 1));
    int seg = (int)(seg_l < 0 ? 0 : (seg_l > MAX_SEG ? MAX_SEG : seg_l));

    size_t out_elems = (size_t)out_size;

    if (seg >= 4) {
        int* counts  = (int*)d_ws;
        int* buckets = counts + (size_t)NSUB * N;

        zero_kernel<<<2048, 256, 0, stream>>>(out, out_elems, counts, NSUB * N);
        bucket_fill_kernel<<<(E + 255) / 256, 256, 0, stream>>>(
            targets, msgs, out, counts, buckets, E, N, seg);
        gather_kernel<<<(N + 3) / 4, 256, 0, stream>>>(
            msgs, counts, buckets, out, E, N, seg);
    } else {
        // tiny-workspace fallback: correctness over speed
        int* counts = (int*)d_ws;  // unused
        zero_kernel<<<2048, 256, 0, stream>>>(out, out_elems, counts, 0);
        scatter_atomic_kernel<<<4096, 256, 0, stream>>>(msgs, targets, out, E, N);
    }
}

// Round 7
// 123.111 us; speedup vs baseline: 1.3651x; 1.0346x over previous
//
#include <hip/hip_runtime.h>

// EdgeSumAggregatorSparse: out[b, t[e], d] += msgs[b, e, d]
// B=2, D=128 hard-coded; E, N derived at launch.

typedef float f32x4 __attribute__((ext_vector_type(4)));

#define D_DIM 128
#define B_DIM 2
#define NSUB 4          // sub-counters per node (atomic contention spread)
#define MAX_SEG 64      // bucket slots per sub-counter (total cap = 256)

// ---------------------------------------------------------------- zero pass
__global__ void zero_kernel(float* __restrict__ out, size_t out_elems,
                            int* __restrict__ counts, int n_counts) {
    size_t i = (size_t)blockIdx.x * blockDim.x + threadIdx.x;
    size_t stride = (size_t)gridDim.x * blockDim.x;
    size_t nv = out_elems / 4;
    f32x4* o4 = reinterpret_cast<f32x4*>(out);
    f32x4 z = 0.f;
    for (size_t j = i; j < nv; j += stride) __builtin_nontemporal_store(z, &o4[j]);
    for (size_t j = nv * 4 + i; j < out_elems; j += stride) out[j] = 0.f;
    for (size_t j = i; j < (size_t)n_counts; j += stride) counts[j] = 0;
}

// ------------------------------------------------------------- bucket fill
// One thread per edge. counts layout: [NSUB][N]; thread picks sub-counter
// s = e & (NSUB-1), claims a slot in segment s of node t's bucket
// (bucket row = NSUB*seg ints). Cached (non-NT) bucket stores: 64B line
// holds 16 slots of one segment, written ~12x before eviction, stays
// L2/L3-resident for the gather. Segment overflow falls back to direct
// fp32 atomics into out (pre-zeroed) — correct for any input.
__global__ void bucket_fill_kernel(const int* __restrict__ targets,
                                   const float* __restrict__ msgs,
                                   float* __restrict__ out,
                                   int* __restrict__ counts,
                                   int* __restrict__ buckets,
                                   int E, int N, int seg) {
    int e = blockIdx.x * blockDim.x + threadIdx.x;
    if (e >= E) return;
    int t = __builtin_nontemporal_load(&targets[e]);
    int s = e & (NSUB - 1);
    int pos = atomicAdd(&counts[s * N + t], 1);
    if (pos < seg) {
        buckets[(size_t)t * (NSUB * seg) + s * seg + pos] = e;
    } else {
        for (int b = 0; b < B_DIM; ++b) {
            const float* src = msgs + ((size_t)b * E + e) * D_DIM;
            float* dst = out + ((size_t)b * N + t) * D_DIM;
            for (int d = 0; d < D_DIM; ++d) atomicAdd(&dst[d], src[d]);
        }
    }
}

// ------------------------------------------------------------------ gather
// One wave per node, 4 waves per 256-thread block.
// lane -> (batch = lane>>5, float4 slot q = lane&31): one wave instruction
// reads BOTH batch rows of an edge = 2 x 512B = 1KB (16B/lane).
// R6: FOUR independent accumulator chains, 4 edges/iter, unroll 4
// -> up to 16 x 1KB loads in flight per wave, quarter the serial
// dependency depth of R4. Probes whether dependency depth is still the
// limiter or we've hit random-512B DRAM efficiency.
__global__ __launch_bounds__(256) void gather_kernel(
        const float* __restrict__ msgs,
        const int* __restrict__ counts,
        const int* __restrict__ buckets,
        float* __restrict__ out,
        int E, int N, int seg) {
    int wave = threadIdx.x >> 6;
    int lane = threadIdx.x & 63;
    int n = blockIdx.x * 4 + wave;
    if (n >= N) return;
    int b = lane >> 5;    // batch
    int q = lane & 31;    // float4 slot within the 128-float row

    f32x4 acc0 = 0.f, acc1 = 0.f, acc2 = 0.f, acc3 = 0.f;
    const float* base = msgs + (size_t)b * E * D_DIM;
    const int* bkrow = buckets + (size_t)n * (NSUB * seg);
    bool overflow = false;

    for (int s = 0; s < NSUB; ++s) {
        int cnt_raw = counts[s * N + n];
        int cnt = cnt_raw < seg ? cnt_raw : seg;
        overflow |= (cnt_raw > seg);
        const int* bk = bkrow + s * seg;
        for (int chunk = 0; chunk < cnt; chunk += 64) {
            int m = cnt - chunk;
            if (m > 64) m = 64;
            int my_e = (lane < m) ? bk[chunk + lane] : 0;   // coalesced stage
            int j = 0;
            #pragma unroll 4
            for (; j + 3 < m; j += 4) {
                int e0 = __shfl(my_e, j);                   // uniform -> readlane
                int e1 = __shfl(my_e, j + 1);
                int e2 = __shfl(my_e, j + 2);
                int e3 = __shfl(my_e, j + 3);
                const f32x4* r0 = reinterpret_cast<const f32x4*>(base + (size_t)e0 * D_DIM);
                const f32x4* r1 = reinterpret_cast<const f32x4*>(base + (size_t)e1 * D_DIM);
                const f32x4* r2 = reinterpret_cast<const f32x4*>(base + (size_t)e2 * D_DIM);
                const f32x4* r3 = reinterpret_cast<const f32x4*>(base + (size_t)e3 * D_DIM);
                acc0 += __builtin_nontemporal_load(&r0[q]);
                acc1 += __builtin_nontemporal_load(&r1[q]);
                acc2 += __builtin_nontemporal_load(&r2[q]);
                acc3 += __builtin_nontemporal_load(&r3[q]);
            }
            for (; j < m; ++j) {
                int e0 = __shfl(my_e, j);
                const f32x4* r0 = reinterpret_cast<const f32x4*>(base + (size_t)e0 * D_DIM);
                acc0 += __builtin_nontemporal_load(&r0[q]);
            }
        }
    }

    f32x4 acc = (acc0 + acc1) + (acc2 + acc3);
    f32x4* o = reinterpret_cast<f32x4*>(out + ((size_t)b * N + n) * D_DIM) + q;
    if (overflow) {
        // overflow contributions already atomically added into out: RMW
        f32x4 cur = *o;
        *o = cur + acc;
    } else {
        __builtin_nontemporal_store(acc, o);   // sole writer, never re-read
    }
}

// --------------------------------------------------- fallback: pure atomics
__global__ void scatter_atomic_kernel(const float* __restrict__ msgs,
                                      const int* __restrict__ targets,
                                      float* __restrict__ out,
                                      int E, int N) {
    size_t total = (size_t)E * D_DIM;
    size_t stride = (size_t)gridDim.x * blockDim.x;
    for (size_t idx = (size_t)blockIdx.x * blockDim.x + threadIdx.x;
         idx < total; idx += stride) {
        int e = (int)(idx >> 7);
        int d = (int)(idx & (D_DIM - 1));
        int t = targets[e];
        atomicAdd(&out[((size_t)0 * N + t) * D_DIM + d],
                  msgs[((size_t)0 * E + e) * D_DIM + d]);
        atomicAdd(&out[((size_t)1 * N + t) * D_DIM + d],
                  msgs[((size_t)1 * E + e) * D_DIM + d]);
    }
}

extern "C" void kernel_launch(void* const* d_in, const int* in_sizes, int n_in,
                              void* d_out, int out_size, void* d_ws, size_t ws_size,
                              hipStream_t stream) {
    const float* msgs    = (const float*)d_in[0];
    const int*   targets = (const int*)d_in[1];
    float*       out     = (float*)d_out;

    const int E = in_sizes[1];
    const int N = out_size / (B_DIM * D_DIM);

    // workspace layout: [ counts: NSUB*N ints ][ buckets: N*NSUB*seg ints ]
    size_t ws_ints = ws_size / sizeof(int);
    long seg_l = ((long)ws_ints - (long)NSUB * N) / ((long)NSUB * (N > 0 ? N : 1));
    int seg = (int)(seg_l < 0 ? 0 : (seg_l > MAX_SEG ? MAX_SEG : seg_l));

    size_t out_elems = (size_t)out_size;

    if (seg >= 4) {
        int* counts  = (int*)d_ws;
        int* buckets = counts + (size_t)NSUB * N;

        zero_kernel<<<2048, 256, 0, stream>>>(out, out_elems, counts, NSUB * N);
        bucket_fill_kernel<<<(E + 255) / 256, 256, 0, stream>>>(
            targets, msgs, out, counts, buckets, E, N, seg);
        gather_kernel<<<(N + 3) / 4, 256, 0, stream>>>(
            msgs, counts, buckets, out, E, N, seg);
    } else {
        // tiny-workspace fallback: correctness over speed
        int* counts = (int*)d_ws;  // unused
        zero_kernel<<<2048, 256, 0, stream>>>(out, out_elems, counts, 0);
        scatter_atomic_kernel<<<4096, 256, 0, stream>>>(msgs, targets, out, E, N);
    }
}